// Round 1
// baseline (489.561 us; speedup 1.0000x reference)
//
#include <hip/hip_runtime.h>
#include <hip/hip_bf16.h>
#include <stdint.h>

// ---- problem constants ----
#define BATCH 4
#define SEQ   8400
#define DM    512
#define KP    8484      // SEQ + 2*42 (edge pad)
#define NWIN  100
#define STEP_ 84
#define PAD_  42
#define NKEY  126       // keys needed per window: x <= max w = 125
#define MROWS 33600     // BATCH*SEQ

typedef __attribute__((ext_vector_type(8))) short short8;
typedef __attribute__((ext_vector_type(4))) float float4v;
typedef __attribute__((ext_vector_type(4))) unsigned short ushort4v;

#define MFMA16 __builtin_amdgcn_mfma_f32_16x16x32_bf16

__device__ __forceinline__ unsigned short f2bf(float f) {
    union { float f; unsigned u; } v; v.f = f;
    return (unsigned short)((v.u + 0x7FFFu + ((v.u >> 16) & 1u)) >> 16);  // RNE
}

// ============ prepass: W (f32 [k][n] 512x512) -> Wt (bf16 [n][k]) ============
__global__ __launch_bounds__(256) void kprep(const float* __restrict__ Wq,
                                             const float* __restrict__ Wk,
                                             const float* __restrict__ Wv,
                                             const float* __restrict__ Wo,
                                             unsigned short* __restrict__ Wt) {
    const float* src = blockIdx.z == 0 ? Wq : blockIdx.z == 1 ? Wk
                     : blockIdx.z == 2 ? Wv : Wo;
    unsigned short* dst = Wt + (size_t)blockIdx.z * DM * DM;
    __shared__ float t[64][65];
    int c = threadIdx.x & 63, r4 = threadIdx.x >> 6;
    int kb = blockIdx.x * 64, nb = blockIdx.y * 64;
    for (int i = 0; i < 16; i++) {
        int r = r4 * 16 + i;
        t[r][c] = src[(size_t)(kb + r) * DM + nb + c];
    }
    __syncthreads();
    for (int i = 0; i < 16; i++) {
        int r = r4 * 16 + i;                       // n-local
        dst[(size_t)(nb + r) * DM + kb + c] = f2bf(t[c][r]);
    }
}

// ============ kernel 1: QKV projection (f32 in, bf16 MFMA, bf16 out) =========
// out layout per tensor: [h*BATCH+b][KP][64]
struct ProjArgs {
    const float* in[3];
    const unsigned short* Wt[3];
    const float* bias[3];
    unsigned short* out[3];
    float scale[3];
};

__global__ __launch_bounds__(256) void kproj(ProjArgs pa) {
    int mt = blockIdx.x;                 // 0..66  (128-row tiles over KP)
    int nt = blockIdx.y;                 // 0..3   (128-col tiles over 512)
    int z  = blockIdx.z;                 // tensor*4 + b
    int ten = z >> 2, b = z & 3;
    const float* A = pa.in[ten] + (size_t)b * SEQ * DM;
    const unsigned short* W = pa.Wt[ten];
    const float* bias = pa.bias[ten];
    unsigned short* O = pa.out[ten];
    float scale = pa.scale[ten];
    int m0 = mt * 128, n0 = nt * 128;

    __shared__ __align__(16) unsigned short Al[128 * 64];
    __shared__ __align__(16) unsigned short Bl[128 * 64];

    int tid = threadIdx.x;
    int lane = tid & 63, wid = tid >> 6;
    int wm = (wid >> 1) * 64, wn = (wid & 1) * 64;
    int l15 = lane & 15, g = lane >> 4;

    float4v acc[4][4];
    for (int i = 0; i < 4; i++)
        for (int j = 0; j < 4; j++) { float4v zz = {0.f,0.f,0.f,0.f}; acc[i][j] = zz; }

    for (int kt = 0; kt < 8; kt++) {
        // stage A: 128 rows x 64 k of f32 (edge-pad gather) -> bf16, swizzled
        for (int c = tid; c < 1024; c += 256) {
            int r = c >> 3, kg = c & 7;
            int p = m0 + r;
            int row = p - PAD_; row = row < 0 ? 0 : (row > SEQ - 1 ? SEQ - 1 : row);
            const float* src = A + (size_t)row * DM + kt * 64 + kg * 8;
            float4v f0 = *(const float4v*)src;
            float4v f1 = *(const float4v*)(src + 4);
            short8 hv;
            hv[0] = (short)f2bf(f0.x); hv[1] = (short)f2bf(f0.y);
            hv[2] = (short)f2bf(f0.z); hv[3] = (short)f2bf(f0.w);
            hv[4] = (short)f2bf(f1.x); hv[5] = (short)f2bf(f1.y);
            hv[6] = (short)f2bf(f1.z); hv[7] = (short)f2bf(f1.w);
            *(short8*)((char*)Al + r * 128 + ((kg ^ (r & 7)) << 4)) = hv;
        }
        // stage B: Wt bf16 [n][k], already K-contiguous
        for (int c = tid; c < 1024; c += 256) {
            int r = c >> 3, kg = c & 7;
            short8 hv = *(const short8*)(W + (size_t)(n0 + r) * DM + kt * 64 + kg * 8);
            *(short8*)((char*)Bl + r * 128 + ((kg ^ (r & 7)) << 4)) = hv;
        }
        __syncthreads();
        for (int ks = 0; ks < 2; ks++) {
            short8 af[4], bf[4];
            for (int i = 0; i < 4; i++) {
                int r = wm + i * 16 + l15;
                int kg = ks * 4 + g;
                af[i] = *(const short8*)((char*)Al + r * 128 + ((kg ^ (r & 7)) << 4));
            }
            for (int j = 0; j < 4; j++) {
                int r = wn + j * 16 + l15;
                int kg = ks * 4 + g;
                bf[j] = *(const short8*)((char*)Bl + r * 128 + ((kg ^ (r & 7)) << 4));
            }
            for (int i = 0; i < 4; i++)
                for (int j = 0; j < 4; j++)
                    acc[i][j] = MFMA16(af[i], bf[j], acc[i][j], 0, 0, 0);
        }
        __syncthreads();
    }
    // epilogue: +bias, *scale, bf16, scatter to head-split layout
    for (int j = 0; j < 4; j++) {
        int n = n0 + wn + j * 16 + l15;
        float bv = bias[n];
        int h = n >> 6, d = n & 63;
        unsigned short* outp = O + (size_t)(h * BATCH + b) * KP * 64 + d;
        for (int i = 0; i < 4; i++) {
            int pbase = m0 + wm + i * 16 + g * 4;
            float4v v = acc[i][j];
            for (int r = 0; r < 4; r++) {
                int p = pbase + r;
                if (p < KP) outp[(size_t)p * 64] = f2bf((v[r] + bv) * scale);
            }
        }
    }
}

// ============ kernel 2: windowed causal attention ============================
// block = (win, hb); 6 waves; queries 84 (padded 96), keys 126 (padded 128)
__global__ __launch_bounds__(384) void kattn(const unsigned short* __restrict__ Qb,
                                             const unsigned short* __restrict__ Kb,
                                             const unsigned short* __restrict__ Vb,
                                             unsigned short* __restrict__ attn) {
    int win = blockIdx.x, hb = blockIdx.y;
    int h = hb >> 2, b = hb & 3;
    const unsigned short* Qg = Qb + (size_t)hb * KP * 64;
    const unsigned short* Kg = Kb + (size_t)hb * KP * 64;
    const unsigned short* Vg = Vb + (size_t)hb * KP * 64;
    int p0 = win * STEP_;

    __shared__ __align__(16) unsigned short Ql[96 * 64];    // reused as O bounce
    __shared__ __align__(16) unsigned short Kl[128 * 64];
    __shared__ __align__(16) unsigned short Vl[64 * 128];   // V^T [d][x] swizzled
    __shared__ __align__(16) unsigned short Pl[96 * 128];   // P  [q][x] swizzled

    int tid = threadIdx.x, lane = tid & 63, f = tid >> 6;   // f = query frag (wave)
    int l15 = lane & 15, g = lane >> 4;

    // ---- stage Q (rows 42..125 of window), K, V (rows 0..125); zero-fill pad
    for (int c = tid; c < 2816; c += 384) {
        if (c < 768) {
            int qi = c >> 3, kg = c & 7;
            short8 hv = {0,0,0,0,0,0,0,0};
            if (qi < 84) hv = *(const short8*)(Qg + (size_t)(p0 + PAD_ + qi) * 64 + kg * 8);
            *(short8*)((char*)Ql + qi * 128 + ((kg ^ (qi & 7)) << 4)) = hv;
        } else if (c < 1792) {
            int cc = c - 768; int x = cc >> 3, kg = cc & 7;
            short8 hv = {0,0,0,0,0,0,0,0};
            if (x < NKEY) hv = *(const short8*)(Kg + (size_t)(p0 + x) * 64 + kg * 8);
            *(short8*)((char*)Kl + x * 128 + ((kg ^ (x & 7)) << 4)) = hv;
        } else {
            int cc = c - 1792; int x = cc >> 3, ch = cc & 7;
            short8 hv = {0,0,0,0,0,0,0,0};
            if (x < NKEY) hv = *(const short8*)(Vg + (size_t)(p0 + x) * 64 + ch * 8);
            for (int e = 0; e < 8; e++) {           // scatter -> V^T[d][x]
                int d = ch * 8 + e;
                int byte = d * 256 + (((x >> 3) ^ (d & 7)) << 4) + (x & 7) * 2;
                *(unsigned short*)((char*)Vl + byte) = (unsigned short)hv[e];
            }
        }
    }
    __syncthreads();

    // ---- S^T = K @ Q^T for this wave's query frag: lane holds col q=f*16+l15
    short8 bq[2];
    {
        int r = f * 16 + l15;
        for (int ks = 0; ks < 2; ks++) {
            int kg = ks * 4 + g;
            bq[ks] = *(const short8*)((char*)Ql + r * 128 + ((kg ^ (r & 7)) << 4));
        }
    }
    float4v st[8];
    for (int xf = 0; xf < 8; xf++) {
        float4v zz = {0.f,0.f,0.f,0.f}; st[xf] = zz;
        for (int ks = 0; ks < 2; ks++) {
            int r = xf * 16 + l15;
            int kg = ks * 4 + g;
            short8 a = *(const short8*)((char*)Kl + r * 128 + ((kg ^ (r & 7)) << 4));
            st[xf] = MFMA16(a, bq[ks], st[xf], 0, 0, 0);
        }
    }

    // ---- causal mask + wave-local softmax over x (rows of S^T)
    int w_abs = PAD_ + f * 16 + l15;
    int w_eff = w_abs > 125 ? 125 : w_abs;          // keep padded queries finite
    float mx = -1e30f;
    for (int xf = 0; xf < 8; xf++)
        for (int r = 0; r < 4; r++) {
            int x = xf * 16 + g * 4 + r;
            float vv = st[xf][r];
            if (x > w_eff) vv = -1e30f;             // also kills x>=126 pad
            st[xf][r] = vv;
            mx = fmaxf(mx, vv);
        }
    mx = fmaxf(mx, __shfl_xor(mx, 16));
    mx = fmaxf(mx, __shfl_xor(mx, 32));
    float s = 0.f;
    for (int xf = 0; xf < 8; xf++)
        for (int r = 0; r < 4; r++) {
            float e = __expf(st[xf][r] - mx);
            st[xf][r] = e;
            s += e;
        }
    s += __shfl_xor(s, 16);
    s += __shfl_xor(s, 32);
    float inv = 1.f / s;

    // ---- P -> LDS bf16 [q][x] swizzled (lane holds 4 consecutive x per frag)
    {
        int qi = f * 16 + l15;
        for (int xf = 0; xf < 8; xf++) {
            ushort4v pw;
            for (int r = 0; r < 4; r++) pw[r] = f2bf(st[xf][r] * inv);
            int xc = 2 * xf + (g >> 1);
            int byte = qi * 256 + ((xc ^ (qi & 7)) << 4) + (g & 1) * 8;
            *(ushort4v*)((char*)Pl + byte) = pw;
        }
    }
    __syncthreads();

    // ---- PV: attn[q][d] = P @ V   (A=P from Pl, B=V from Vl=V^T)
    float4v pv[4];
    for (int j = 0; j < 4; j++) { float4v zz = {0.f,0.f,0.f,0.f}; pv[j] = zz; }
    int qi = f * 16 + l15;
    for (int g2 = 0; g2 < 4; g2++) {
        int xc = g2 * 4 + g;
        short8 a = *(const short8*)((char*)Pl + qi * 256 + ((xc ^ (qi & 7)) << 4));
        for (int j = 0; j < 4; j++) {
            int d = j * 16 + l15;
            short8 bvv = *(const short8*)((char*)Vl + d * 256 + ((xc ^ (d & 7)) << 4));
            pv[j] = MFMA16(a, bvv, pv[j], 0, 0, 0);
        }
    }

    // ---- bounce to LDS (reuse Ql) for coalesced bf16 global write
    unsigned short* Ol = Ql;
    for (int j = 0; j < 4; j++) {
        int d = j * 16 + l15;
        for (int r = 0; r < 4; r++) {
            int q = f * 16 + g * 4 + r;
            int byte = q * 128 + ((((d >> 3) ^ (q & 7))) << 4) + (d & 7) * 2;
            *(unsigned short*)((char*)Ol + byte) = f2bf(pv[j][r]);
        }
    }
    __syncthreads();
    for (int c = tid; c < 672; c += 384) {          // 84 rows x 8 chunks
        int q = c >> 3, ch = c & 7;
        short8 hv = *(const short8*)((char*)Ol + q * 128 + ((ch ^ (q & 7)) << 4));
        size_t off = ((size_t)(b * SEQ + win * STEP_ + q) * DM) + h * 64 + ch * 8;
        *(short8*)(attn + off) = hv;
    }
}

// ============ kernel 3: output projection (bf16 A, f32 out + bias) ===========
__global__ __launch_bounds__(256) void kout(const unsigned short* __restrict__ Abuf,
                                            const unsigned short* __restrict__ W,
                                            const float* __restrict__ bias,
                                            float* __restrict__ Out) {
    int m0 = blockIdx.x * 128, n0 = blockIdx.y * 128;
    __shared__ __align__(16) unsigned short Al[128 * 64];
    __shared__ __align__(16) unsigned short Bl[128 * 64];
    int tid = threadIdx.x;
    int lane = tid & 63, wid = tid >> 6;
    int wm = (wid >> 1) * 64, wn = (wid & 1) * 64;
    int l15 = lane & 15, g = lane >> 4;

    float4v acc[4][4];
    for (int i = 0; i < 4; i++)
        for (int j = 0; j < 4; j++) { float4v zz = {0.f,0.f,0.f,0.f}; acc[i][j] = zz; }

    for (int kt = 0; kt < 8; kt++) {
        for (int c = tid; c < 1024; c += 256) {
            int r = c >> 3, kg = c & 7;
            int row = m0 + r; if (row > MROWS - 1) row = MROWS - 1;
            short8 hv = *(const short8*)(Abuf + (size_t)row * DM + kt * 64 + kg * 8);
            *(short8*)((char*)Al + r * 128 + ((kg ^ (r & 7)) << 4)) = hv;
        }
        for (int c = tid; c < 1024; c += 256) {
            int r = c >> 3, kg = c & 7;
            short8 hv = *(const short8*)(W + (size_t)(n0 + r) * DM + kt * 64 + kg * 8);
            *(short8*)((char*)Bl + r * 128 + ((kg ^ (r & 7)) << 4)) = hv;
        }
        __syncthreads();
        for (int ks = 0; ks < 2; ks++) {
            short8 af[4], bf[4];
            for (int i = 0; i < 4; i++) {
                int r = wm + i * 16 + l15;
                int kg = ks * 4 + g;
                af[i] = *(const short8*)((char*)Al + r * 128 + ((kg ^ (r & 7)) << 4));
            }
            for (int j = 0; j < 4; j++) {
                int r = wn + j * 16 + l15;
                int kg = ks * 4 + g;
                bf[j] = *(const short8*)((char*)Bl + r * 128 + ((kg ^ (r & 7)) << 4));
            }
            for (int i = 0; i < 4; i++)
                for (int j = 0; j < 4; j++)
                    acc[i][j] = MFMA16(af[i], bf[j], acc[i][j], 0, 0, 0);
        }
        __syncthreads();
    }
    for (int j = 0; j < 4; j++) {
        int n = n0 + wn + j * 16 + l15;
        float bv = bias[n];
        for (int i = 0; i < 4; i++) {
            int rbase = m0 + wm + i * 16 + g * 4;
            float4v v = acc[i][j];
            for (int r = 0; r < 4; r++) {
                int row = rbase + r;
                if (row < MROWS) Out[(size_t)row * DM + n] = v[r] + bv;
            }
        }
    }
}

// ============ launch =========================================================
extern "C" void kernel_launch(void* const* d_in, const int* in_sizes, int n_in,
                              void* d_out, int out_size, void* d_ws, size_t ws_size,
                              hipStream_t stream) {
    const float* q  = (const float*)d_in[0];
    const float* k  = (const float*)d_in[1];
    const float* v  = (const float*)d_in[2];
    const float* Wq = (const float*)d_in[3];
    const float* bq = (const float*)d_in[4];
    const float* Wk = (const float*)d_in[5];
    const float* bk = (const float*)d_in[6];
    const float* Wv = (const float*)d_in[7];
    const float* bv = (const float*)d_in[8];
    const float* Wo = (const float*)d_in[9];
    const float* bo = (const float*)d_in[10];

    // workspace layout (ushort elements)
    const size_t WT_ELEMS  = (size_t)4 * DM * DM;          //  1,048,576
    const size_t QKV_ELEMS = (size_t)32 * KP * 64;         // 17,375,232 each
    const size_t ATT_ELEMS = (size_t)MROWS * DM;           // 17,203,200
    size_t need = (WT_ELEMS + 3 * QKV_ELEMS + ATT_ELEMS) * 2;
    if (ws_size < need) return;                            // fail loudly (zeros)

    unsigned short* Wt = (unsigned short*)d_ws;
    unsigned short* Qb = Wt + WT_ELEMS;
    unsigned short* Kb = Qb + QKV_ELEMS;
    unsigned short* Vb = Kb + QKV_ELEMS;
    unsigned short* Ab = Vb + QKV_ELEMS;

    kprep<<<dim3(8, 8, 4), dim3(256), 0, stream>>>(Wq, Wk, Wv, Wo, Wt);

    ProjArgs pa;
    pa.in[0] = q;  pa.in[1] = k;  pa.in[2] = v;
    pa.Wt[0] = Wt;            pa.Wt[1] = Wt + DM * DM;  pa.Wt[2] = Wt + 2 * DM * DM;
    pa.bias[0] = bq; pa.bias[1] = bk; pa.bias[2] = bv;
    pa.out[0] = Qb; pa.out[1] = Kb; pa.out[2] = Vb;
    pa.scale[0] = 0.07715167498104595f;  // 1/sqrt(168), folded into Q
    pa.scale[1] = 1.f; pa.scale[2] = 1.f;
    kproj<<<dim3(67, 4, 12), dim3(256), 0, stream>>>(pa);

    kattn<<<dim3(NWIN, 32), dim3(384), 0, stream>>>(Qb, Kb, Vb, Ab);

    kout<<<dim3(263, 4), dim3(256), 0, stream>>>(Ab, Wt + 3 * DM * DM, bo,
                                                 (float*)d_out);
}

// Round 2
// 309.565 us; speedup vs baseline: 1.5814x; 1.5814x over previous
//
#include <hip/hip_runtime.h>
#include <stdint.h>

// ---- problem constants ----
#define BATCH 4
#define SEQ   8400
#define DM    512
#define KP    8484      // SEQ + 2*42 (edge pad)
#define NWIN  100
#define STEP_ 84
#define PAD_  42
#define NKEY  126       // keys needed per window: x <= max w = 125
#define MROWS 33600     // BATCH*SEQ

typedef __attribute__((ext_vector_type(8))) short short8;
typedef __attribute__((ext_vector_type(4))) float float4v;
typedef __attribute__((ext_vector_type(4))) unsigned short ushort4v;

#define MFMA16 __builtin_amdgcn_mfma_f32_16x16x32_bf16

__device__ __forceinline__ unsigned short f2bf(float f) {
    union { float f; unsigned u; } v; v.f = f;
    return (unsigned short)((v.u + 0x7FFFu + ((v.u >> 16) & 1u)) >> 16);  // RNE
}

// async global->LDS, 16B per lane; LDS dest = wave-uniform base + lane*16
typedef __attribute__((address_space(1))) const unsigned int as1_cu32;
typedef __attribute__((address_space(3))) unsigned int as3_u32;
__device__ __forceinline__ void gload16(const void* g, void* l) {
    __builtin_amdgcn_global_load_lds((as1_cu32*)g, (as3_u32*)l, 16, 0, 0);
}

// ============ prepass: W (f32 [k][n] 512x512) -> Wt (bf16 [n][k]) ============
__global__ __launch_bounds__(256) void kprep(const float* __restrict__ Wq,
                                             const float* __restrict__ Wk,
                                             const float* __restrict__ Wv,
                                             const float* __restrict__ Wo,
                                             unsigned short* __restrict__ Wt) {
    const float* src = blockIdx.z == 0 ? Wq : blockIdx.z == 1 ? Wk
                     : blockIdx.z == 2 ? Wv : Wo;
    unsigned short* dst = Wt + (size_t)blockIdx.z * DM * DM;
    __shared__ float t[64][65];
    int c = threadIdx.x & 63, r4 = threadIdx.x >> 6;
    int kb = blockIdx.x * 64, nb = blockIdx.y * 64;
    for (int i = 0; i < 16; i++) {
        int r = r4 * 16 + i;
        t[r][c] = src[(size_t)(kb + r) * DM + nb + c];
    }
    __syncthreads();
    for (int i = 0; i < 16; i++) {
        int r = r4 * 16 + i;                       // n-local
        dst[(size_t)(nb + r) * DM + kb + c] = f2bf(t[c][r]);
    }
}

// ============ pass 0b: pad + convert q/k/v -> bf16 Apad[z][KP][512] ==========
__global__ __launch_bounds__(256) void kcvt(const float* __restrict__ q,
                                            const float* __restrict__ k,
                                            const float* __restrict__ v,
                                            unsigned short* __restrict__ Apad) {
    int cid = blockIdx.x * 256 + threadIdx.x;      // < 3*4*KP*64 = 6,515,712
    int ch = cid & 63;
    int pz = cid >> 6;
    int p = pz % KP;
    int z = pz / KP;                               // ten*4 + b
    int ten = z >> 2, b = z & 3;
    const float* in = ten == 0 ? q : ten == 1 ? k : v;
    int row = p - PAD_; row = row < 0 ? 0 : (row > SEQ - 1 ? SEQ - 1 : row);
    const float* src = in + ((size_t)b * SEQ + row) * DM + ch * 8;
    float4v f0 = *(const float4v*)src;
    float4v f1 = *(const float4v*)(src + 4);
    short8 hv;
    hv[0] = (short)f2bf(f0.x); hv[1] = (short)f2bf(f0.y);
    hv[2] = (short)f2bf(f0.z); hv[3] = (short)f2bf(f0.w);
    hv[4] = (short)f2bf(f1.x); hv[5] = (short)f2bf(f1.y);
    hv[6] = (short)f2bf(f1.z); hv[7] = (short)f2bf(f1.w);
    *(short8*)(Apad + (size_t)cid * 8) = hv;
}

// ============ kernel 1: QKV projection (all-bf16, global_load_lds staging) ===
// out layout per tensor: [h*BATCH+b][KP][64]
__global__ __launch_bounds__(256) void kproj(const unsigned short* __restrict__ Apad,
                                             const unsigned short* __restrict__ Wt,
                                             const float* __restrict__ bq,
                                             const float* __restrict__ bk,
                                             const float* __restrict__ bv,
                                             unsigned short* __restrict__ Qb,
                                             unsigned short* __restrict__ Kb,
                                             unsigned short* __restrict__ Vb) {
    int mt = blockIdx.x, nt = blockIdx.y, z = blockIdx.z;
    int ten = z >> 2, b = z & 3;
    const unsigned short* A = Apad + (size_t)z * KP * DM;
    const unsigned short* W = Wt + (size_t)ten * DM * DM;
    const float* bias = ten == 0 ? bq : ten == 1 ? bk : bv;
    unsigned short* O = ten == 0 ? Qb : ten == 1 ? Kb : Vb;
    float scale = ten == 0 ? 0.07715167498104595f : 1.f;   // 1/sqrt(168) into Q
    int m0 = mt * 128, n0 = nt * 128;

    // 34,816 B: [0,16K) = Al, [16K,32K) = Bl during K-loop; whole = Ol after
    __shared__ __align__(16) unsigned short lds[17408];
    unsigned short* Al = lds;
    unsigned short* Bl = lds + 8192;

    int tid = threadIdx.x, lane = tid & 63, w = tid >> 6;
    int wm = (w >> 1) * 64, wn = (w & 1) * 64;
    int l15 = lane & 15, g = lane >> 4;

    float4v acc[4][4];
    for (int i = 0; i < 4; i++)
        for (int j = 0; j < 4; j++) { float4v zz = {0.f,0.f,0.f,0.f}; acc[i][j] = zz; }

    for (int kt = 0; kt < 8; kt++) {
        // stage A,B: linear LDS dest, XOR-pre-swizzled global source (m173)
        for (int it = 0; it < 4; it++) {
            int c = w * 256 + it * 64 + lane;
            int r = c >> 3, kgl = c & 7;
            int kg = kgl ^ (r & 7);
            int row = m0 + r; if (row > KP - 1) row = KP - 1;
            gload16(A + (size_t)row * DM + kt * 64 + kg * 8,
                    (char*)Al + (w * 256 + it * 64) * 16);
        }
        for (int it = 0; it < 4; it++) {
            int c = w * 256 + it * 64 + lane;
            int r = c >> 3, kgl = c & 7;
            int kg = kgl ^ (r & 7);
            gload16(W + (size_t)(n0 + r) * DM + kt * 64 + kg * 8,
                    (char*)Bl + (w * 256 + it * 64) * 16);
        }
        __syncthreads();
        for (int ks = 0; ks < 2; ks++) {
            short8 af[4], bfr[4];
            for (int i = 0; i < 4; i++) {
                int r = wm + i * 16 + l15, kg = ks * 4 + g;
                af[i] = *(const short8*)((char*)Al + r * 128 + ((kg ^ (r & 7)) << 4));
            }
            for (int j = 0; j < 4; j++) {
                int r = wn + j * 16 + l15, kg = ks * 4 + g;
                bfr[j] = *(const short8*)((char*)Bl + r * 128 + ((kg ^ (r & 7)) << 4));
            }
            for (int i = 0; i < 4; i++)
                for (int j = 0; j < 4; j++)
                    acc[i][j] = MFMA16(af[i], bfr[j], acc[i][j], 0, 0, 0);
        }
        __syncthreads();
    }

    // epilogue: bias+scale -> bf16 -> LDS bounce (stride 136 us = 272B, 16B-aligned)
    unsigned short* Ol = lds;
    for (int j = 0; j < 4; j++) {
        int nl = wn + j * 16 + l15;
        float bval = bias[n0 + nl];
        for (int i = 0; i < 4; i++) {
            float4v vv = acc[i][j];
            for (int r = 0; r < 4; r++) {
                int qr = wm + i * 16 + g * 4 + r;
                Ol[qr * 136 + nl] = f2bf((vv[r] + bval) * scale);
            }
        }
    }
    __syncthreads();
    int hbase = n0 >> 6;
    for (int c = tid; c < 2048; c += 256) {        // 128 rows x 2 heads x 8 chunks
        int qr = c >> 4, hh = (c >> 3) & 1, ch = c & 7;
        int p = m0 + qr;
        if (p < KP) {
            int h = hbase + hh;
            *(short8*)(O + ((size_t)(h * BATCH + b) * KP + p) * 64 + ch * 8) =
                *(const short8*)(Ol + qr * 136 + hh * 64 + ch * 8);
        }
    }
}

// ============ kernel 2: windowed causal attention (unchanged) ================
__global__ __launch_bounds__(384) void kattn(const unsigned short* __restrict__ Qb,
                                             const unsigned short* __restrict__ Kb,
                                             const unsigned short* __restrict__ Vb,
                                             unsigned short* __restrict__ attn) {
    int win = blockIdx.x, hb = blockIdx.y;
    int h = hb >> 2, b = hb & 3;
    const unsigned short* Qg = Qb + (size_t)hb * KP * 64;
    const unsigned short* Kg = Kb + (size_t)hb * KP * 64;
    const unsigned short* Vg = Vb + (size_t)hb * KP * 64;
    int p0 = win * STEP_;

    __shared__ __align__(16) unsigned short Ql[96 * 64];    // reused as O bounce
    __shared__ __align__(16) unsigned short Kl[128 * 64];
    __shared__ __align__(16) unsigned short Vl[64 * 128];   // V^T [d][x] swizzled
    __shared__ __align__(16) unsigned short Pl[96 * 128];   // P  [q][x] swizzled

    int tid = threadIdx.x, lane = tid & 63, f = tid >> 6;
    int l15 = lane & 15, g = lane >> 4;

    for (int c = tid; c < 2816; c += 384) {
        if (c < 768) {
            int qi = c >> 3, kg = c & 7;
            short8 hv = {0,0,0,0,0,0,0,0};
            if (qi < 84) hv = *(const short8*)(Qg + (size_t)(p0 + PAD_ + qi) * 64 + kg * 8);
            *(short8*)((char*)Ql + qi * 128 + ((kg ^ (qi & 7)) << 4)) = hv;
        } else if (c < 1792) {
            int cc = c - 768; int x = cc >> 3, kg = cc & 7;
            short8 hv = {0,0,0,0,0,0,0,0};
            if (x < NKEY) hv = *(const short8*)(Kg + (size_t)(p0 + x) * 64 + kg * 8);
            *(short8*)((char*)Kl + x * 128 + ((kg ^ (x & 7)) << 4)) = hv;
        } else {
            int cc = c - 1792; int x = cc >> 3, ch = cc & 7;
            short8 hv = {0,0,0,0,0,0,0,0};
            if (x < NKEY) hv = *(const short8*)(Vg + (size_t)(p0 + x) * 64 + ch * 8);
            for (int e = 0; e < 8; e++) {           // scatter -> V^T[d][x]
                int d = ch * 8 + e;
                int byte = d * 256 + (((x >> 3) ^ (d & 7)) << 4) + (x & 7) * 2;
                *(unsigned short*)((char*)Vl + byte) = (unsigned short)hv[e];
            }
        }
    }
    __syncthreads();

    short8 bq2[2];
    {
        int r = f * 16 + l15;
        for (int ks = 0; ks < 2; ks++) {
            int kg = ks * 4 + g;
            bq2[ks] = *(const short8*)((char*)Ql + r * 128 + ((kg ^ (r & 7)) << 4));
        }
    }
    float4v st[8];
    for (int xf = 0; xf < 8; xf++) {
        float4v zz = {0.f,0.f,0.f,0.f}; st[xf] = zz;
        for (int ks = 0; ks < 2; ks++) {
            int r = xf * 16 + l15;
            int kg = ks * 4 + g;
            short8 a = *(const short8*)((char*)Kl + r * 128 + ((kg ^ (r & 7)) << 4));
            st[xf] = MFMA16(a, bq2[ks], st[xf], 0, 0, 0);
        }
    }

    int w_abs = PAD_ + f * 16 + l15;
    int w_eff = w_abs > 125 ? 125 : w_abs;
    float mx = -1e30f;
    for (int xf = 0; xf < 8; xf++)
        for (int r = 0; r < 4; r++) {
            int x = xf * 16 + g * 4 + r;
            float vv = st[xf][r];
            if (x > w_eff) vv = -1e30f;
            st[xf][r] = vv;
            mx = fmaxf(mx, vv);
        }
    mx = fmaxf(mx, __shfl_xor(mx, 16));
    mx = fmaxf(mx, __shfl_xor(mx, 32));
    float s = 0.f;
    for (int xf = 0; xf < 8; xf++)
        for (int r = 0; r < 4; r++) {
            float e = __expf(st[xf][r] - mx);
            st[xf][r] = e;
            s += e;
        }
    s += __shfl_xor(s, 16);
    s += __shfl_xor(s, 32);
    float inv = 1.f / s;

    {
        int qi = f * 16 + l15;
        for (int xf = 0; xf < 8; xf++) {
            ushort4v pw;
            for (int r = 0; r < 4; r++) pw[r] = f2bf(st[xf][r] * inv);
            int xc = 2 * xf + (g >> 1);
            int byte = qi * 256 + ((xc ^ (qi & 7)) << 4) + (g & 1) * 8;
            *(ushort4v*)((char*)Pl + byte) = pw;
        }
    }
    __syncthreads();

    float4v pv[4];
    for (int j = 0; j < 4; j++) { float4v zz = {0.f,0.f,0.f,0.f}; pv[j] = zz; }
    int qi = f * 16 + l15;
    for (int g2 = 0; g2 < 4; g2++) {
        int xc = g2 * 4 + g;
        short8 a = *(const short8*)((char*)Pl + qi * 256 + ((xc ^ (qi & 7)) << 4));
        for (int j = 0; j < 4; j++) {
            int d = j * 16 + l15;
            short8 bvv = *(const short8*)((char*)Vl + d * 256 + ((xc ^ (d & 7)) << 4));
            pv[j] = MFMA16(a, bvv, pv[j], 0, 0, 0);
        }
    }

    unsigned short* Ol = Ql;
    for (int j = 0; j < 4; j++) {
        int d = j * 16 + l15;
        for (int r = 0; r < 4; r++) {
            int qq = f * 16 + g * 4 + r;
            int byte = qq * 128 + ((((d >> 3) ^ (qq & 7))) << 4) + (d & 7) * 2;
            *(unsigned short*)((char*)Ol + byte) = f2bf(pv[j][r]);
        }
    }
    __syncthreads();
    for (int c = tid; c < 672; c += 384) {
        int qq = c >> 3, ch = c & 7;
        short8 hv = *(const short8*)((char*)Ol + qq * 128 + ((ch ^ (qq & 7)) << 4));
        size_t off = ((size_t)(b * SEQ + win * STEP_ + qq) * DM) + h * 64 + ch * 8;
        *(short8*)(attn + off) = hv;
    }
}

// ============ kernel 3: output projection (bf16 in, f32 out + bias) ==========
__global__ __launch_bounds__(256) void kout(const unsigned short* __restrict__ Ab,
                                            const unsigned short* __restrict__ W,
                                            const float* __restrict__ bias,
                                            float* __restrict__ Out) {
    int m0 = blockIdx.x * 128, n0 = blockIdx.y * 128;
    __shared__ __align__(16) unsigned short lds[16384];
    unsigned short* Al = lds;
    unsigned short* Bl = lds + 8192;
    int tid = threadIdx.x, lane = tid & 63, w = tid >> 6;
    int wm = (w >> 1) * 64, wn = (w & 1) * 64;
    int l15 = lane & 15, g = lane >> 4;

    float4v acc[4][4];
    for (int i = 0; i < 4; i++)
        for (int j = 0; j < 4; j++) { float4v zz = {0.f,0.f,0.f,0.f}; acc[i][j] = zz; }

    for (int kt = 0; kt < 8; kt++) {
        for (int it = 0; it < 4; it++) {
            int c = w * 256 + it * 64 + lane;
            int r = c >> 3, kgl = c & 7;
            int kg = kgl ^ (r & 7);
            int row = m0 + r; if (row > MROWS - 1) row = MROWS - 1;
            gload16(Ab + (size_t)row * DM + kt * 64 + kg * 8,
                    (char*)Al + (w * 256 + it * 64) * 16);
        }
        for (int it = 0; it < 4; it++) {
            int c = w * 256 + it * 64 + lane;
            int r = c >> 3, kgl = c & 7;
            int kg = kgl ^ (r & 7);
            gload16(W + (size_t)(n0 + r) * DM + kt * 64 + kg * 8,
                    (char*)Bl + (w * 256 + it * 64) * 16);
        }
        __syncthreads();
        for (int ks = 0; ks < 2; ks++) {
            short8 af[4], bfr[4];
            for (int i = 0; i < 4; i++) {
                int r = wm + i * 16 + l15, kg = ks * 4 + g;
                af[i] = *(const short8*)((char*)Al + r * 128 + ((kg ^ (r & 7)) << 4));
            }
            for (int j = 0; j < 4; j++) {
                int r = wn + j * 16 + l15, kg = ks * 4 + g;
                bfr[j] = *(const short8*)((char*)Bl + r * 128 + ((kg ^ (r & 7)) << 4));
            }
            for (int i = 0; i < 4; i++)
                for (int j = 0; j < 4; j++)
                    acc[i][j] = MFMA16(af[i], bfr[j], acc[i][j], 0, 0, 0);
        }
        __syncthreads();
    }
    for (int j = 0; j < 4; j++) {
        int n = n0 + wn + j * 16 + l15;
        float bv = bias[n];
        for (int i = 0; i < 4; i++) {
            int rbase = m0 + wm + i * 16 + g * 4;
            float4v v = acc[i][j];
            for (int r = 0; r < 4; r++) {
                int row = rbase + r;
                if (row < MROWS) Out[(size_t)row * DM + n] = v[r] + bv;
            }
        }
    }
}

// ============ launch =========================================================
extern "C" void kernel_launch(void* const* d_in, const int* in_sizes, int n_in,
                              void* d_out, int out_size, void* d_ws, size_t ws_size,
                              hipStream_t stream) {
    const float* q  = (const float*)d_in[0];
    const float* k  = (const float*)d_in[1];
    const float* v  = (const float*)d_in[2];
    const float* Wq = (const float*)d_in[3];
    const float* bq = (const float*)d_in[4];
    const float* Wk = (const float*)d_in[5];
    const float* bk = (const float*)d_in[6];
    const float* Wv = (const float*)d_in[7];
    const float* bv = (const float*)d_in[8];
    const float* Wo = (const float*)d_in[9];
    const float* bo = (const float*)d_in[10];

    // workspace layout (ushort elements)
    const size_t WT_ELEMS  = (size_t)4 * DM * DM;          //  1,048,576
    const size_t QKV_ELEMS = (size_t)32 * KP * 64;         // 17,375,232 each
    const size_t SCR_ELEMS = (size_t)12 * KP * DM;         // 26,050,560 (Apad / attn alias)
    size_t need = (WT_ELEMS + 3 * QKV_ELEMS + SCR_ELEMS) * 2;   // ~158.4 MB
    if (ws_size < need) return;

    unsigned short* Wt = (unsigned short*)d_ws;
    unsigned short* Qb = Wt + WT_ELEMS;
    unsigned short* Kb = Qb + QKV_ELEMS;
    unsigned short* Vb = Kb + QKV_ELEMS;
    unsigned short* SCR = Vb + QKV_ELEMS;   // Apad (kcvt->kproj), then attn (kattn->kout)

    kprep<<<dim3(8, 8, 4), dim3(256), 0, stream>>>(Wq, Wk, Wv, Wo, Wt);
    kcvt<<<dim3(25452), dim3(256), 0, stream>>>(q, k, v, SCR);
    kproj<<<dim3(67, 4, 12), dim3(256), 0, stream>>>(SCR, Wt, bq, bk, bv, Qb, Kb, Vb);
    kattn<<<dim3(NWIN, 32), dim3(384), 0, stream>>>(Qb, Kb, Vb, SCR);
    kout<<<dim3(263, 4), dim3(256), 0, stream>>>(SCR, Wt + 3 * DM * DM, bo,
                                                 (float*)d_out);
}

// Round 3
// 229.461 us; speedup vs baseline: 2.1335x; 1.3491x over previous
//
#include <hip/hip_runtime.h>
#include <hip/hip_bf16.h>
#include <stdint.h>

// ---- problem constants ----
#define BATCH 4
#define SEQ   8400
#define DM    512
#define KP    8484      // SEQ + 2*42 (edge pad)
#define NWIN  100
#define STEP_ 84
#define PAD_  42
#define NKEY  126
#define MROWS 33600     // BATCH*SEQ

typedef __attribute__((ext_vector_type(8))) short short8;
typedef __attribute__((ext_vector_type(4))) float float4v;
typedef __attribute__((ext_vector_type(4))) unsigned short ushort4v;

#define MFMA16 __builtin_amdgcn_mfma_f32_16x16x32_bf16

__device__ __forceinline__ unsigned short f2bf(float f) {
    union { float f; unsigned u; } v; v.f = f;
    return (unsigned short)((v.u + 0x7FFFu + ((v.u >> 16) & 1u)) >> 16);  // RNE
}
// compiler-friendly cast (emits v_cvt_pk_bf16_f32 for pairs; RNE)
__device__ __forceinline__ unsigned short bfc(float f) {
    __hip_bfloat16 h = __float2bfloat16(f);
    union { __hip_bfloat16 h; unsigned short u; } v; v.h = h;
    return v.u;
}

typedef __attribute__((address_space(1))) const unsigned int as1_cu32;
typedef __attribute__((address_space(3))) unsigned int as3_u32;
__device__ __forceinline__ void gload16(const void* g, void* l) {
    __builtin_amdgcn_global_load_lds((as1_cu32*)g, (as3_u32*)l, 16, 0, 0);
}

// ============ prepass: W (f32 [k][n] 512x512) -> Wt (bf16 [n][k]) ============
__global__ __launch_bounds__(256) void kprep(const float* __restrict__ Wq,
                                             const float* __restrict__ Wk,
                                             const float* __restrict__ Wv,
                                             const float* __restrict__ Wo,
                                             unsigned short* __restrict__ Wt) {
    const float* src = blockIdx.z == 0 ? Wq : blockIdx.z == 1 ? Wk
                     : blockIdx.z == 2 ? Wv : Wo;
    unsigned short* dst = Wt + (size_t)blockIdx.z * DM * DM;
    __shared__ float t[64][65];
    int c = threadIdx.x & 63, r4 = threadIdx.x >> 6;
    int kb = blockIdx.x * 64, nb = blockIdx.y * 64;
    for (int i = 0; i < 16; i++) {
        int r = r4 * 16 + i;
        t[r][c] = src[(size_t)(kb + r) * DM + nb + c];
    }
    __syncthreads();
    for (int i = 0; i < 16; i++) {
        int r = r4 * 16 + i;
        dst[(size_t)(nb + r) * DM + kb + c] = f2bf(t[c][r]);
    }
}

// ============ kernel 1: fused pad+cvt+QKV projection =========================
// BM=64, BN=512 (A read once). A = f32 input with edge-pad gather.
// Q/K out: [h*B+b][p][64]; V out transposed: VT[h*B+b][d][p].
__global__ __launch_bounds__(256, 2) void kproj(const float* __restrict__ q,
                                                const float* __restrict__ k,
                                                const float* __restrict__ v,
                                                const unsigned short* __restrict__ Wt,
                                                const float* __restrict__ bq,
                                                const float* __restrict__ bk,
                                                const float* __restrict__ bv,
                                                unsigned short* __restrict__ Qb,
                                                unsigned short* __restrict__ Kb,
                                                unsigned short* __restrict__ VT) {
    int mt = blockIdx.x, z = blockIdx.y;
    int ten = z >> 2, b = z & 3;
    const float* A = (ten == 0 ? q : ten == 1 ? k : v) + (size_t)b * SEQ * DM;
    const unsigned short* W = Wt + (size_t)ten * DM * DM;
    const float* bias = ten == 0 ? bq : ten == 1 ? bk : bv;
    float scale = ten == 0 ? 0.07715167498104595f : 1.f;   // 1/sqrt(168)
    int m0 = mt * 64;

    // [0,16K) A-tile f32 [64][64]; [16K,80K) B-tile bf16 [512][64]
    __shared__ __align__(16) char lds[81920];

    int tid = threadIdx.x, lane = tid & 63, wc = tid >> 6;
    int l15 = lane & 15, g = lane >> 4;

    float4v acc[4][8];
#pragma unroll
    for (int i = 0; i < 4; i++)
#pragma unroll
        for (int j = 0; j < 8; j++) { float4v zz = {0.f,0.f,0.f,0.f}; acc[i][j] = zz; }

    for (int kt = 0; kt < 8; kt++) {
        // stage A (f32, pad-gather, pre-swizzled source -> linear LDS)
#pragma unroll
        for (int it = 0; it < 4; it++) {
            int c = it * 256 + tid;
            int r = c >> 4;
            int c4 = (c & 15) ^ (r & 15);
            int p = m0 + r; if (p > KP - 1) p = KP - 1;
            int row = p - PAD_; row = row < 0 ? 0 : (row > SEQ - 1 ? SEQ - 1 : row);
            gload16(A + (size_t)row * DM + kt * 64 + c4 * 4,
                    lds + it * 4096 + wc * 1024);
        }
        // stage B (bf16 W^T [512][64], pre-swizzled source)
#pragma unroll
        for (int it = 0; it < 16; it++) {
            int c = it * 256 + tid;
            int r = c >> 3;
            int kg = (c & 7) ^ (r & 7);
            gload16(W + (size_t)r * DM + kt * 64 + kg * 8,
                    lds + 16384 + it * 4096 + wc * 1024);
        }
        __syncthreads();
#pragma unroll
        for (int ks = 0; ks < 2; ks++) {
            short8 af[4];
#pragma unroll
            for (int i = 0; i < 4; i++) {
                int r = i * 16 + l15;
                int c4a = (ks * 4 + g) * 2;
                float4v f0 = *(const float4v*)(lds + r * 256 + ((c4a ^ l15) << 4));
                float4v f1 = *(const float4v*)(lds + r * 256 + (((c4a + 1) ^ l15) << 4));
                short8 hv;
                hv[0] = (short)bfc(f0.x); hv[1] = (short)bfc(f0.y);
                hv[2] = (short)bfc(f0.z); hv[3] = (short)bfc(f0.w);
                hv[4] = (short)bfc(f1.x); hv[5] = (short)bfc(f1.y);
                hv[6] = (short)bfc(f1.z); hv[7] = (short)bfc(f1.w);
                af[i] = hv;
            }
            short8 bfr[8];
#pragma unroll
            for (int j = 0; j < 8; j++) {
                int r = wc * 128 + j * 16 + l15;
                int kg = ks * 4 + g;
                bfr[j] = *(const short8*)(lds + 16384 + r * 128 + ((kg ^ (r & 7)) << 4));
            }
#pragma unroll
            for (int i = 0; i < 4; i++)
#pragma unroll
                for (int j = 0; j < 8; j++)
                    acc[i][j] = MFMA16(af[i], bfr[j], acc[i][j], 0, 0, 0);
        }
        __syncthreads();
    }

    if (ten <= 1) {
        // bounce [64][520] u16 then coalesced short8 head-split writes
        unsigned short* Ol = (unsigned short*)lds;
#pragma unroll
        for (int j = 0; j < 8; j++) {
            int n = wc * 128 + j * 16 + l15;
            float bval = bias[n];
#pragma unroll
            for (int i = 0; i < 4; i++) {
                float4v vv = acc[i][j];
#pragma unroll
                for (int r = 0; r < 4; r++)
                    Ol[(i * 16 + g * 4 + r) * 520 + n] = f2bf((vv[r] + bval) * scale);
            }
        }
        __syncthreads();
        unsigned short* O = ten == 0 ? Qb : Kb;
        for (int c = tid; c < 4096; c += 256) {        // 64 rows x 64 chunks
            int row = c >> 6, n8 = c & 63;
            int p = m0 + row;
            if (p < KP) {
                int h = n8 >> 3, ch = n8 & 7;
                *(short8*)(O + ((size_t)(h * BATCH + b) * KP + p) * 64 + ch * 8) =
                    *(const short8*)(Ol + row * 520 + n8 * 8);
            }
        }
    } else {
        // V: direct transposed stores VT[hb][d][p] (lane has 4 consecutive p)
#pragma unroll
        for (int j = 0; j < 8; j++) {
            int n = wc * 128 + j * 16 + l15;
            float bval = bias[n];
            int h = n >> 6, d = n & 63;
            unsigned short* base = VT + ((size_t)(h * BATCH + b) * 64 + d) * KP;
#pragma unroll
            for (int i = 0; i < 4; i++) {
                int p = m0 + i * 16 + g * 4;
                if (p <= KP - 4) {
                    float4v vv = acc[i][j];
                    ushort4v wv;
                    wv[0] = f2bf(vv.x + bval); wv[1] = f2bf(vv.y + bval);
                    wv[2] = f2bf(vv.z + bval); wv[3] = f2bf(vv.w + bval);
                    *(ushort4v*)(base + p) = wv;
                }
            }
        }
    }
}

// ============ kernel 2: windowed causal attention ============================
// block = (win, hb); 6 waves; V already transposed in global (VT[hb][d][p])
__global__ __launch_bounds__(384) void kattn(const unsigned short* __restrict__ Qb,
                                             const unsigned short* __restrict__ Kb,
                                             const unsigned short* __restrict__ VT,
                                             unsigned short* __restrict__ attn) {
    int win = blockIdx.x, hb = blockIdx.y;
    int h = hb >> 2, b = hb & 3;
    const unsigned short* Qg = Qb + (size_t)hb * KP * 64;
    const unsigned short* Kg = Kb + (size_t)hb * KP * 64;
    const unsigned short* Vt = VT + (size_t)hb * 64 * KP;
    int p0 = win * STEP_;

    // Ql [0,12288) 96x64; Kl [12288,28672) 128x64; Vl [28672,45056) 64x128;
    // Pl [45056,69632) 96x128. Ol reuses Ql.
    __shared__ __align__(16) char lds[69632];

    int tid = threadIdx.x, lane = tid & 63, f = tid >> 6;
    int l15 = lane & 15, g = lane >> 4;

    // ---- stage Q (rows p0+42..p0+137) and K (rows p0..p0+127) via gload16
#pragma unroll
    for (int it = 0; it < 5; it++) {
        int base = it * 384 + f * 64;
        if (base < 768) {                       // Q chunks
            int c = base + lane;
            int qi = c >> 3, kg = (c & 7) ^ (qi & 7);
            gload16(Qg + (size_t)(p0 + PAD_ + qi) * 64 + kg * 8, lds + base * 16);
        } else if (base < 1792) {               // K chunks
            int c = base + lane - 768;
            int x = c >> 3, kg = (c & 7) ^ (x & 7);
            gload16(Kg + (size_t)(p0 + x) * 64 + kg * 8, lds + base * 16);
        }
    }
    // ---- stage V^T rows d, x in [p0,p0+128): 8B loads + swizzled ds_write
    for (int c = tid; c < 2048; c += 384) {
        int d = c >> 5, c2 = c & 31;
        ushort4v wv = *(const ushort4v*)(Vt + (size_t)d * KP + p0 + c2 * 4);
        int cx = c2 >> 1;
        *(ushort4v*)(lds + 28672 + d * 256 + (((cx ^ (d & 7)) << 4) | ((c2 & 1) * 8))) = wv;
    }
    __syncthreads();

    // ---- S^T = K @ Q^T (wave f owns query frag q = f*16+l15)
    short8 bq2[2];
    {
        int r = f * 16 + l15;
#pragma unroll
        for (int ks = 0; ks < 2; ks++) {
            int kg = ks * 4 + g;
            bq2[ks] = *(const short8*)(lds + r * 128 + ((kg ^ (r & 7)) << 4));
        }
    }
    float4v st[8];
#pragma unroll
    for (int xf = 0; xf < 8; xf++) {
        float4v zz = {0.f,0.f,0.f,0.f}; st[xf] = zz;
#pragma unroll
        for (int ks = 0; ks < 2; ks++) {
            int r = xf * 16 + l15;
            int kg = ks * 4 + g;
            short8 a = *(const short8*)(lds + 12288 + r * 128 + ((kg ^ (r & 7)) << 4));
            st[xf] = MFMA16(a, bq2[ks], st[xf], 0, 0, 0);
        }
    }

    // ---- causal mask + wave-local softmax
    int w_abs = PAD_ + f * 16 + l15;
    int w_eff = w_abs > 125 ? 125 : w_abs;
    float mx = -1e30f;
#pragma unroll
    for (int xf = 0; xf < 8; xf++)
#pragma unroll
        for (int r = 0; r < 4; r++) {
            int x = xf * 16 + g * 4 + r;
            float vv = st[xf][r];
            if (x > w_eff) vv = -1e30f;
            st[xf][r] = vv;
            mx = fmaxf(mx, vv);
        }
    mx = fmaxf(mx, __shfl_xor(mx, 16));
    mx = fmaxf(mx, __shfl_xor(mx, 32));
    float s = 0.f;
#pragma unroll
    for (int xf = 0; xf < 8; xf++)
#pragma unroll
        for (int r = 0; r < 4; r++) {
            float e = __expf(st[xf][r] - mx);
            st[xf][r] = e;
            s += e;
        }
    s += __shfl_xor(s, 16);
    s += __shfl_xor(s, 32);
    float inv = 1.f / s;

    // ---- P -> Pl bf16 [q][x] swizzled
    {
        int qi = f * 16 + l15;
#pragma unroll
        for (int xf = 0; xf < 8; xf++) {
            ushort4v pw;
#pragma unroll
            for (int r = 0; r < 4; r++) pw[r] = f2bf(st[xf][r] * inv);
            int xc = 2 * xf + (g >> 1);
            *(ushort4v*)(lds + 45056 + qi * 256 + ((xc ^ (qi & 7)) << 4) + (g & 1) * 8) = pw;
        }
    }
    __syncthreads();

    // ---- PV
    float4v pv[4];
#pragma unroll
    for (int j = 0; j < 4; j++) { float4v zz = {0.f,0.f,0.f,0.f}; pv[j] = zz; }
    int qi = f * 16 + l15;
#pragma unroll
    for (int g2 = 0; g2 < 4; g2++) {
        int xc = g2 * 4 + g;
        short8 a = *(const short8*)(lds + 45056 + qi * 256 + ((xc ^ (qi & 7)) << 4));
#pragma unroll
        for (int j = 0; j < 4; j++) {
            int d = j * 16 + l15;
            short8 bvv = *(const short8*)(lds + 28672 + d * 256 + ((xc ^ (d & 7)) << 4));
            pv[j] = MFMA16(a, bvv, pv[j], 0, 0, 0);
        }
    }

    // ---- bounce to LDS (Ql region) then coalesced global write
    unsigned short* Ol = (unsigned short*)lds;
#pragma unroll
    for (int j = 0; j < 4; j++) {
        int d = j * 16 + l15;
#pragma unroll
        for (int r = 0; r < 4; r++) {
            int qq = f * 16 + g * 4 + r;
            int byte = qq * 128 + ((((d >> 3) ^ (qq & 7))) << 4) + (d & 7) * 2;
            *(unsigned short*)((char*)Ol + byte) = f2bf(pv[j][r]);
        }
    }
    __syncthreads();
    for (int c = tid; c < 672; c += 384) {
        int qq = c >> 3, ch = c & 7;
        short8 hv = *(const short8*)((char*)Ol + qq * 128 + ((ch ^ (qq & 7)) << 4));
        size_t off = ((size_t)(b * SEQ + win * STEP_ + qq) * DM) + h * 64 + ch * 8;
        *(short8*)(attn + off) = hv;
    }
}

// ============ kernel 3: output projection, BM=64/BN=512 ======================
__global__ __launch_bounds__(256, 2) void kout(const unsigned short* __restrict__ Ab,
                                               const unsigned short* __restrict__ W,
                                               const float* __restrict__ bias,
                                               float* __restrict__ Out) {
    int m0 = blockIdx.x * 64;
    // [0,8K) A [64][64] bf16; [8K,72K) B [512][64] bf16
    __shared__ __align__(16) char lds[73728];
    int tid = threadIdx.x, lane = tid & 63, wc = tid >> 6;
    int l15 = lane & 15, g = lane >> 4;

    float4v acc[4][8];
#pragma unroll
    for (int i = 0; i < 4; i++)
#pragma unroll
        for (int j = 0; j < 8; j++) { float4v zz = {0.f,0.f,0.f,0.f}; acc[i][j] = zz; }

    for (int kt = 0; kt < 8; kt++) {
#pragma unroll
        for (int it = 0; it < 2; it++) {
            int c = it * 256 + tid;
            int r = c >> 3;
            int kg = (c & 7) ^ (r & 7);
            gload16(Ab + (size_t)(m0 + r) * DM + kt * 64 + kg * 8,
                    lds + it * 4096 + wc * 1024);
        }
#pragma unroll
        for (int it = 0; it < 16; it++) {
            int c = it * 256 + tid;
            int r = c >> 3;
            int kg = (c & 7) ^ (r & 7);
            gload16(W + (size_t)r * DM + kt * 64 + kg * 8,
                    lds + 8192 + it * 4096 + wc * 1024);
        }
        __syncthreads();
#pragma unroll
        for (int ks = 0; ks < 2; ks++) {
            short8 af[4];
#pragma unroll
            for (int i = 0; i < 4; i++) {
                int r = i * 16 + l15;
                int kg = ks * 4 + g;
                af[i] = *(const short8*)(lds + r * 128 + ((kg ^ (r & 7)) << 4));
            }
            short8 bfr[8];
#pragma unroll
            for (int j = 0; j < 8; j++) {
                int r = wc * 128 + j * 16 + l15;
                int kg = ks * 4 + g;
                bfr[j] = *(const short8*)(lds + 8192 + r * 128 + ((kg ^ (r & 7)) << 4));
            }
#pragma unroll
            for (int i = 0; i < 4; i++)
#pragma unroll
                for (int j = 0; j < 8; j++)
                    acc[i][j] = MFMA16(af[i], bfr[j], acc[i][j], 0, 0, 0);
        }
        __syncthreads();
    }
#pragma unroll
    for (int j = 0; j < 8; j++) {
        int n = wc * 128 + j * 16 + l15;
        float bv = bias[n];
#pragma unroll
        for (int i = 0; i < 4; i++) {
            float4v vv = acc[i][j];
#pragma unroll
            for (int r = 0; r < 4; r++) {
                int m = m0 + i * 16 + g * 4 + r;
                Out[(size_t)m * DM + n] = vv[r] + bv;
            }
        }
    }
}

// ============ launch =========================================================
extern "C" void kernel_launch(void* const* d_in, const int* in_sizes, int n_in,
                              void* d_out, int out_size, void* d_ws, size_t ws_size,
                              hipStream_t stream) {
    const float* q  = (const float*)d_in[0];
    const float* k  = (const float*)d_in[1];
    const float* v  = (const float*)d_in[2];
    const float* Wq = (const float*)d_in[3];
    const float* bq = (const float*)d_in[4];
    const float* Wk = (const float*)d_in[5];
    const float* bk = (const float*)d_in[6];
    const float* Wv = (const float*)d_in[7];
    const float* bv = (const float*)d_in[8];
    const float* Wo = (const float*)d_in[9];
    const float* bo = (const float*)d_in[10];

    const size_t WT_ELEMS  = (size_t)4 * DM * DM;          //  1,048,576
    const size_t QKV_ELEMS = (size_t)32 * KP * 64;         // 17,375,232 each
    const size_t ATT_ELEMS = (size_t)MROWS * DM;           // 17,203,200
    size_t need = (WT_ELEMS + 3 * QKV_ELEMS + ATT_ELEMS) * 2;   // ~140.8 MB
    if (ws_size < need) return;

    unsigned short* Wt = (unsigned short*)d_ws;
    unsigned short* Qb = Wt + WT_ELEMS;
    unsigned short* Kb = Qb + QKV_ELEMS;
    unsigned short* VT = Kb + QKV_ELEMS;
    unsigned short* Ab = VT + QKV_ELEMS;

    kprep<<<dim3(8, 8, 4), dim3(256), 0, stream>>>(Wq, Wk, Wv, Wo, Wt);
    kproj<<<dim3(133, 12), dim3(256), 0, stream>>>(q, k, v, Wt, bq, bk, bv,
                                                   Qb, Kb, VT);
    kattn<<<dim3(NWIN, 32), dim3(384), 0, stream>>>(Qb, Kb, VT, Ab);
    kout<<<dim3(525), dim3(256), 0, stream>>>(Ab, Wt + 3 * DM * DM, bo,
                                              (float*)d_out);
}